// Round 11
// baseline (1654.710 us; speedup 1.0000x reference)
//
#include <hip/hip_runtime.h>
#include <hip/hip_bf16.h>
#include <math.h>

#define NSAMP 8
#define BATCH 1024
#define PH 12
#define XS 256
#define ZS 32
#define RNN 512
#define LSZ 8
#define INP 290          // LPS + ZS + XS
#define NTOT 8192        // NSAMP * BATCH
#define DT 0.4f

// output layout (flat f32, concatenated in return order)
#define LOGPI_OFF 0
#define MUS_OFF   (NTOT*PH)               // 98304
#define LSIG_OFF  (MUS_OFF + NTOT*PH*2)   // 294912
#define CORR_OFF  (LSIG_OFF + NTOT*PH*2)  // 491520
#define PRED_OFF  (CORR_OFF + NTOT*PH)    // 589824

typedef float f32x4 __attribute__((ext_vector_type(4)));
typedef __bf16 bf16x8 __attribute__((ext_vector_type(8)));

__device__ __forceinline__ float sigmoid_(float x) {
    return 1.0f / (1.0f + __expf(-x));
}
__device__ __forceinline__ float tanh_(float x) {
    return 1.0f - 2.0f / (__expf(2.0f * x) + 1.0f);
}
__device__ __forceinline__ unsigned short f2bfu(float v) {
    __hip_bfloat16 b = __float2bfloat16(v);
    return __builtin_bit_cast(unsigned short, b);
}
__device__ __forceinline__ float bfu2f(unsigned short u) {
    return __uint_as_float(((unsigned)u) << 16);
}
__device__ __forceinline__ float bflo(unsigned u) { return __uint_as_float(u << 16); }
__device__ __forceinline__ float bfhi(unsigned u) { return __uint_as_float(u & 0xffff0000u); }

__device__ __forceinline__ void async16(const void* g, void* l) {
    __builtin_amdgcn_global_load_lds((const __attribute__((address_space(1))) void*)g,
                                     (__attribute__((address_space(3))) void*)l, 16, 0, 0);
}

// ---------------- prep: zx cast + a0 ----------------
__global__ void k_prep1(const float* __restrict__ z, const float* __restrict__ x,
                        const float* __restrict__ x_r_t0,
                        const float* __restrict__ W_sa, const float* __restrict__ b_sa,
                        __hip_bfloat16* __restrict__ zx, float* __restrict__ a) {
    int n = blockIdx.x, k = threadIdx.x;
    if (k < 288) {
        float v = (k < 32) ? z[n * ZS + k] : x[(n & (BATCH - 1)) * XS + (k - 32)];
        zx[(size_t)n * 288 + k] = __float2bfloat16(v);
    } else if (k == 288) {
        int b = n & (BATCH - 1);
        float a0 = b_sa[0], a1 = b_sa[1];
#pragma unroll
        for (int kk = 0; kk < LSZ; ++kk) {
            float xv = x_r_t0[b * LSZ + kk];
            a0 = fmaf(xv, W_sa[0 * LSZ + kk], a0);
            a1 = fmaf(xv, W_sa[1 * LSZ + kk], a1);
        }
        a[n * 2 + 0] = a0;
        a[n * 2 + 1] = a1;
    }
}

// ---------------- prep: Wcat cast (for gemm0) ----------------
__global__ void k_prep_wcat(const float* __restrict__ W_h0, const float* __restrict__ W_ih,
                            __hip_bfloat16* __restrict__ Wcat) {
    int r = blockIdx.x, k = threadIdx.x;
    if (k >= 288) return;
    float v = (r < RNN) ? W_h0[r * 288 + k] : W_ih[(size_t)(r - RNN) * INP + k];
    Wcat[(size_t)r * 288 + k] = __float2bfloat16(v);
}

// ---------------- prep: pack Whh into B-frag stream layout ----------------
// frag f3 = cf3*16 + kf (cf3 = g*32 + ch); lane (fq,fr) holds
//   Whh[g*512 + ch*16 + fr][kf*32 + fq*8 + e]
__global__ void k_prep_wp(const float* __restrict__ W_hh, unsigned short* __restrict__ Wp) {
    int idx = blockIdx.x * 512 + threadIdx.x;     // 0..98303
    int cf3 = idx >> 10, kf = (idx >> 6) & 15, lane = idx & 63;
    int fq = lane >> 4, fr = lane & 15;
    int g = cf3 >> 5, ch = cf3 & 31;
    const float* src = W_hh + (size_t)(g * 512 + ch * 16 + fr) * RNN + kf * 32 + fq * 8;
    unsigned short pk[8];
#pragma unroll
    for (int e = 0; e < 8; ++e) pk[e] = f2bfu(src[e]);
    *reinterpret_cast<uint4*>(Wp + (size_t)idx * 8) = *reinterpret_cast<uint4*>(pk);
}

// ---------------- prep: pack head weights (16 cols: mu0,mu1,ls0,ls1,corr,0..) ----------------
__global__ void k_prep_whp(const float* __restrict__ W_mu, const float* __restrict__ W_ls,
                           const float* __restrict__ W_corr, unsigned short* __restrict__ Whp) {
    int idx = blockIdx.x * 256 + threadIdx.x;     // 0..1023
    int kf = idx >> 6, lane = idx & 63;
    int fq = lane >> 4, fr = lane & 15;
    int k0 = kf * 32 + fq * 8;
    unsigned short pk[8];
#pragma unroll
    for (int e = 0; e < 8; ++e) {
        float v = 0.f;
        if (fr < 2)      v = W_mu[fr * RNN + k0 + e];
        else if (fr < 4) v = W_ls[(fr - 2) * RNN + k0 + e];
        else if (fr == 4) v = W_corr[k0 + e];
        pk[e] = f2bfu(v);
    }
    *reinterpret_cast<uint4*>(Whp + (size_t)idx * 8) = *reinterpret_cast<uint4*>(pk);
}

// ---------------- GEMM0: [h0 | gi] = zx @ Wcat^T + bias (plain row-major, proven) ----------
__global__ __launch_bounds__(256, 2) void k_gemm0_mfma(
    const __hip_bfloat16* __restrict__ zx, const __hip_bfloat16* __restrict__ Wcat,
    const float* __restrict__ b_h0, const float* __restrict__ b_ih,
    __hip_bfloat16* __restrict__ h0, __hip_bfloat16* __restrict__ gi)
{
    __shared__ __align__(16) char sAB[2][16384];
    const int tid = threadIdx.x;
    const int wv = tid >> 6, lane = tid & 63;
    const int fq = lane >> 4, fr = lane & 15;
    const int wr = wv >> 1, wc = wv & 1;
    const int tile_r = blockIdx.x * 128, tile_c = blockIdx.y * 128;

    f32x4 acc[4][4];
#pragma unroll
    for (int i = 0; i < 4; ++i)
#pragma unroll
        for (int j = 0; j < 4; ++j) acc[i][j] = (f32x4){0.f, 0.f, 0.f, 0.f};

    auto stage = [&](int b, int k0) {
#pragma unroll
        for (int j = 0; j < 2; ++j) {
            int ck = wv * 2 + j;
            int row = ck * 16 + (lane >> 2);
            int slot = lane & 3;
            async16(zx + (size_t)(tile_r + row) * 288 + k0 + ((slot ^ (row & 3)) << 3),
                    sAB[b] + ck * 1024 + lane * 16);
        }
#pragma unroll
        for (int j = 0; j < 2; ++j) {
            int ck = wv * 2 + j;
            int row = ck * 16 + (lane >> 2);
            int slot = lane & 3;
            async16(Wcat + (size_t)(tile_c + row) * 288 + k0 + ((slot ^ (row & 3)) << 3),
                    sAB[b] + 8192 + ck * 1024 + lane * 16);
        }
    };

    auto compute = [&](int b) {
        bf16x8 af[4], bv[4];
#pragma unroll
        for (int i = 0; i < 4; ++i) {
            int r = wr * 64 + i * 16 + fr;
            af[i] = *(const bf16x8*)(sAB[b] + r * 64 + ((fq ^ (r & 3)) << 4));
        }
#pragma unroll
        for (int j = 0; j < 4; ++j) {
            int r = wc * 64 + j * 16 + fr;
            bv[j] = *(const bf16x8*)(sAB[b] + 8192 + r * 64 + ((fq ^ (r & 3)) << 4));
        }
#pragma unroll
        for (int i = 0; i < 4; ++i)
#pragma unroll
            for (int j = 0; j < 4; ++j)
                acc[i][j] = __builtin_amdgcn_mfma_f32_16x16x32_bf16(af[i], bv[j], acc[i][j], 0, 0, 0);
    };

    stage(0, 0);
    __syncthreads();
    int buf = 0;
#pragma unroll 1
    for (int t = 0; t < 9; ++t) {
        if (t < 8) stage(buf ^ 1, (t + 1) * 32);
        compute(buf);
        __syncthreads();
        buf ^= 1;
    }

#pragma unroll
    for (int jn = 0; jn < 4; ++jn) {
        int cg = tile_c + wc * 64 + jn * 16 + fr;
        float bias = (cg < RNN) ? b_h0[cg] : b_ih[cg - RNN];
#pragma unroll
        for (int i = 0; i < 4; ++i)
#pragma unroll
            for (int q = 0; q < 4; ++q) {
                int rg = tile_r + wr * 64 + i * 16 + fq * 4 + q;
                float v = acc[i][jn][q] + bias;
                if (cg < RNN) h0[(size_t)rg * RNN + cg] = __float2bfloat16(v);
                else          gi[(size_t)rg * 1536 + (cg - RNN)] = __float2bfloat16(v);
            }
    }
}

// ---------------- persistent rollout: 256 blocks x 32 rows, all 12 steps ----------------
__global__ __launch_bounds__(512, 1) void k_rollout(
    const unsigned short* __restrict__ h0B, const unsigned short* __restrict__ giB,
    const unsigned short* __restrict__ Wp, const unsigned short* __restrict__ Whp,
    const float* __restrict__ a0,
    const float* __restrict__ b_hh, const float* __restrict__ W_ih,
    const float* __restrict__ b_mu, const float* __restrict__ b_ls,
    const float* __restrict__ b_corr,
    const float* __restrict__ eps_step, const float* __restrict__ eps_final,
    const float* __restrict__ p0,
    float* __restrict__ out)
{
    __shared__ __align__(16) char ldsH[32768];     // h in A-frag layout, XOR-swizzled
    __shared__ __align__(16) char ldsWh[16384];    // head-W B-frags
    __shared__ float ldsBhh[1536];
    __shared__ float ldsWih[1536 * 2];
    __shared__ float ldsP[32 * 17];
    __shared__ float ldsA[32 * 2];

    const int tid = threadIdx.x;
    const int wv = tid >> 6, lane = tid & 63;
    const int fq = lane >> 4, fr = lane & 15;
    const int blk = blockIdx.x;

    // ---- per-thread init: h0 -> ldsH (via the SAME address formula the epilogue uses),
    //      gi -> registers (loop-invariant), packed as bf16 pairs ----
    uint2 giRZ[2][2][4];
    uint2 giN[2][4];
#pragma unroll
    for (int rf = 0; rf < 2; ++rf)
#pragma unroll
        for (int cf = 0; cf < 4; ++cf) {
            const int col = wv * 64 + cf * 16 + fr;
            const int frag = rf * 16 + wv * 2 + (cf >> 1);
            const int sw = (frag & 7) << 4;
            unsigned short rq[4], zq[4], nq[4];
#pragma unroll
            for (int q = 0; q < 4; ++q) {
                const int row = rf * 16 + fq * 4 + q;
                const size_t n = (size_t)blk * 32 + row;
                rq[q] = giB[n * 1536 + col];
                zq[q] = giB[n * 1536 + 512 + col];
                nq[q] = giB[n * 1536 + 1024 + col];
                const int slot = (fq * 4 + q) + 16 * ((cf & 1) * 2 + (fr >> 3));
                const int ad = frag * 1024 + ((slot * 16) ^ sw) + (fr & 7) * 2;
                *reinterpret_cast<unsigned short*>(ldsH + ad) = h0B[n * RNN + col];
            }
            giRZ[0][rf][cf] = make_uint2((unsigned)rq[0] | ((unsigned)rq[1] << 16),
                                         (unsigned)rq[2] | ((unsigned)rq[3] << 16));
            giRZ[1][rf][cf] = make_uint2((unsigned)zq[0] | ((unsigned)zq[1] << 16),
                                         (unsigned)zq[2] | ((unsigned)zq[3] << 16));
            giN[rf][cf]     = make_uint2((unsigned)nq[0] | ((unsigned)nq[1] << 16),
                                         (unsigned)nq[2] | ((unsigned)nq[3] << 16));
        }

#pragma unroll
    for (int u0 = 0; u0 < 2; ++u0) {
        int u = u0 * 512 + tid;
        *reinterpret_cast<uint4*>(ldsWh + u * 16) =
            *reinterpret_cast<const uint4*>(Whp + (size_t)u * 8);
    }
#pragma unroll
    for (int c0 = 0; c0 < 3; ++c0) {
        int c3 = c0 * 512 + tid;
        ldsBhh[c3] = b_hh[c3];
        ldsWih[c3 * 2 + 0] = W_ih[(size_t)c3 * INP + 288];
        ldsWih[c3 * 2 + 1] = W_ih[(size_t)c3 * INP + 289];
    }
    float cx = 0.f, cy = 0.f, px = 0.f, py = 0.f;
    float bm0 = 0, bm1 = 0, bl0 = 0, bl1 = 0, bc0 = 0;
    if (tid < 32) {
        const int n = blk * 32 + tid;
        ldsA[tid * 2 + 0] = a0[n * 2 + 0];
        ldsA[tid * 2 + 1] = a0[n * 2 + 1];
        px = p0[(n & (BATCH - 1)) * 2 + 0];
        py = p0[(n & (BATCH - 1)) * 2 + 1];
        bm0 = b_mu[0]; bm1 = b_mu[1]; bl0 = b_ls[0]; bl1 = b_ls[1]; bc0 = b_corr[0];
    }
    __syncthreads();

    const char* wpB = (const char*)Wp + (size_t)wv * 65536 + lane * 16;

#pragma unroll 1
    for (int t = 0; t < PH; ++t) {
        // ---- acc init: r,z gates from registers; n gate zero ----
        f32x4 acc[3][2][4];
#pragma unroll
        for (int g = 0; g < 2; ++g)
#pragma unroll
            for (int rf = 0; rf < 2; ++rf)
#pragma unroll
                for (int cf = 0; cf < 4; ++cf) {
                    acc[g][rf][cf][0] = bflo(giRZ[g][rf][cf].x);
                    acc[g][rf][cf][1] = bfhi(giRZ[g][rf][cf].x);
                    acc[g][rf][cf][2] = bflo(giRZ[g][rf][cf].y);
                    acc[g][rf][cf][3] = bfhi(giRZ[g][rf][cf].y);
                }
#pragma unroll
        for (int rf = 0; rf < 2; ++rf)
#pragma unroll
            for (int cf = 0; cf < 4; ++cf) acc[2][rf][cf] = (f32x4){0.f, 0.f, 0.f, 0.f};

        // ---- K-loop: A from LDS h, B streamed from global (no barriers) ----
#pragma unroll
        for (int kf = 0; kf < 16; ++kf) {
            const int sw = (kf & 7) << 4;
            bf16x8 af0 = *(const bf16x8*)(ldsH + kf * 1024 + ((lane * 16) ^ sw));
            bf16x8 af1 = *(const bf16x8*)(ldsH + (16 + kf) * 1024 + ((lane * 16) ^ sw));
#pragma unroll
            for (int g = 0; g < 3; ++g)
#pragma unroll
                for (int cf = 0; cf < 4; ++cf) {
                    bf16x8 bv = *reinterpret_cast<const bf16x8*>(
                        wpB + (size_t)g * 524288 + cf * 16384 + kf * 1024);
                    acc[g][0][cf] = __builtin_amdgcn_mfma_f32_16x16x32_bf16(af0, bv, acc[g][0][cf], 0, 0, 0);
                    acc[g][1][cf] = __builtin_amdgcn_mfma_f32_16x16x32_bf16(af1, bv, acc[g][1][cf], 0, 0, 0);
                }
        }

        // ---- epilogue: gates -> h_new (registers), reads h_old + a + weights ----
        float hnv[2][4][4];
        int haddr[2][4][4];
#pragma unroll
        for (int rf = 0; rf < 2; ++rf)
#pragma unroll
            for (int cf = 0; cf < 4; ++cf) {
                const int frag = rf * 16 + wv * 2 + (cf >> 1);
                const int sw = (frag & 7) << 4;
                const int col = wv * 64 + cf * 16 + fr;
                const float bhr = ldsBhh[col], bhz = ldsBhh[512 + col], bhn = ldsBhh[1024 + col];
                const float wr0 = ldsWih[col * 2], wr1 = ldsWih[col * 2 + 1];
                const float wz0 = ldsWih[(512 + col) * 2], wz1 = ldsWih[(512 + col) * 2 + 1];
                const float wn0 = ldsWih[(1024 + col) * 2], wn1 = ldsWih[(1024 + col) * 2 + 1];
#pragma unroll
                for (int q = 0; q < 4; ++q) {
                    const int row = rf * 16 + fq * 4 + q;
                    const int slot = (fq * 4 + q) + 16 * ((cf & 1) * 2 + (fr >> 3));
                    const int ad = frag * 1024 + ((slot * 16) ^ sw) + (fr & 7) * 2;
                    haddr[rf][cf][q] = ad;
                    const float hold = bfu2f(*reinterpret_cast<const unsigned short*>(ldsH + ad));
                    const float av0 = ldsA[row * 2 + 0], av1 = ldsA[row * 2 + 1];
                    const float gni0 = (q == 0) ? bflo(giN[rf][cf].x) :
                                       (q == 1) ? bfhi(giN[rf][cf].x) :
                                       (q == 2) ? bflo(giN[rf][cf].y) : bfhi(giN[rf][cf].y);
                    const float gr = acc[0][rf][cf][q] + bhr + av0 * wr0 + av1 * wr1;
                    const float gz = acc[1][rf][cf][q] + bhz + av0 * wz0 + av1 * wz1;
                    const float gni = gni0 + av0 * wn0 + av1 * wn1;
                    const float r_ = sigmoid_(gr);
                    const float u_ = sigmoid_(gz);
                    const float n_ = tanh_(gni + r_ * (acc[2][rf][cf][q] + bhn));
                    hnv[rf][cf][q] = (1.0f - u_) * n_ + u_ * hold;
                }
            }
        __syncthreads();   // all reads of ldsH done
#pragma unroll
        for (int rf = 0; rf < 2; ++rf)
#pragma unroll
            for (int cf = 0; cf < 4; ++cf)
#pragma unroll
                for (int q = 0; q < 4; ++q)
                    *reinterpret_cast<unsigned short*>(ldsH + haddr[rf][cf][q]) = f2bfu(hnv[rf][cf][q]);
        __syncthreads();   // h_new visible

        // ---- heads: P = h_new @ Whead^T (wave 0 only) ----
        if (wv == 0) {
            f32x4 hacc[2];
            hacc[0] = (f32x4){0.f, 0.f, 0.f, 0.f};
            hacc[1] = (f32x4){0.f, 0.f, 0.f, 0.f};
#pragma unroll
            for (int kf = 0; kf < 16; ++kf) {
                const int sw = (kf & 7) << 4;
                bf16x8 af0 = *(const bf16x8*)(ldsH + kf * 1024 + ((lane * 16) ^ sw));
                bf16x8 af1 = *(const bf16x8*)(ldsH + (16 + kf) * 1024 + ((lane * 16) ^ sw));
                bf16x8 bh = *(const bf16x8*)(ldsWh + kf * 1024 + lane * 16);
                hacc[0] = __builtin_amdgcn_mfma_f32_16x16x32_bf16(af0, bh, hacc[0], 0, 0, 0);
                hacc[1] = __builtin_amdgcn_mfma_f32_16x16x32_bf16(af1, bh, hacc[1], 0, 0, 0);
            }
#pragma unroll
            for (int rf = 0; rf < 2; ++rf)
#pragma unroll
                for (int q = 0; q < 4; ++q)
                    ldsP[(rf * 16 + fq * 4 + q) * 17 + fr] = hacc[rf][q];
        }
        __syncthreads();

        // ---- sampler: one thread per row (heads tail + k_final folded) ----
        if (tid < 32) {
            const int n = blk * 32 + tid;
            const float mu0 = ldsP[tid * 17 + 0] + bm0;
            const float mu1 = ldsP[tid * 17 + 1] + bm1;
            const float ls0 = ldsP[tid * 17 + 2] + bl0;
            const float ls1 = ldsP[tid * 17 + 3] + bl1;
            const float rho = tanh_(ldsP[tid * 17 + 4] + bc0);
            out[MUS_OFF + (n * PH + t) * 2 + 0] = mu0;
            out[MUS_OFF + (n * PH + t) * 2 + 1] = mu1;
            out[LSIG_OFF + (n * PH + t) * 2 + 0] = ls0;
            out[LSIG_OFF + (n * PH + t) * 2 + 1] = ls1;
            out[CORR_OFF + n * PH + t] = rho;
            out[LOGPI_OFF + n * PH + t] = 1.0f;
            const float sg0 = __expf(ls0), sg1 = __expf(ls1);
            const float rt = sqrtf(fmaxf(1e-5f, 1.0f - rho * rho));
            const float es0 = eps_step[((size_t)t * NTOT + n) * 2 + 0];
            const float es1 = eps_step[((size_t)t * NTOT + n) * 2 + 1];
            ldsA[tid * 2 + 0] = mu0 + sg0 * es0;
            ldsA[tid * 2 + 1] = mu1 + sg1 * (rho * es0 + rt * es1);
            const float ef0 = eps_final[((size_t)n * PH + t) * 2 + 0];
            const float ef1 = eps_final[((size_t)n * PH + t) * 2 + 1];
            cx += mu0 + sg0 * ef0;
            cy += mu1 + sg1 * (rho * ef0 + rt * ef1);
            out[PRED_OFF + (n * PH + t) * 2 + 0] = cx * DT + px;
            out[PRED_OFF + (n * PH + t) * 2 + 1] = cy * DT + py;
        }
        __syncthreads();
    }
}

extern "C" void kernel_launch(void* const* d_in, const int* in_sizes, int n_in,
                              void* d_out, int out_size, void* d_ws, size_t ws_size,
                              hipStream_t stream) {
    const float* x        = (const float*)d_in[0];
    const float* x_r_t0   = (const float*)d_in[1];
    const float* z        = (const float*)d_in[2];
    const float* p0       = (const float*)d_in[3];
    const float* eps_step = (const float*)d_in[4];
    const float* eps_fin  = (const float*)d_in[5];
    const float* W_sa     = (const float*)d_in[6];
    const float* b_sa     = (const float*)d_in[7];
    const float* W_ih     = (const float*)d_in[8];
    const float* b_ih     = (const float*)d_in[9];
    const float* W_hh     = (const float*)d_in[10];
    const float* b_hh     = (const float*)d_in[11];
    const float* W_h0     = (const float*)d_in[12];
    const float* b_h0     = (const float*)d_in[13];
    const float* W_mu     = (const float*)d_in[14];
    const float* b_mu     = (const float*)d_in[15];
    const float* W_ls     = (const float*)d_in[16];
    const float* b_ls     = (const float*)d_in[17];
    const float* W_corr   = (const float*)d_in[18];
    const float* b_corr   = (const float*)d_in[19];

    char* wp = (char*)d_ws;
    float* a             = (float*)wp;           wp += (size_t)NTOT * 2 * 4;
    __hip_bfloat16* zxb  = (__hip_bfloat16*)wp;  wp += (size_t)NTOT * 288 * 2;
    __hip_bfloat16* Wcat = (__hip_bfloat16*)wp;  wp += (size_t)2048 * 288 * 2;
    unsigned short* Wp   = (unsigned short*)wp;  wp += (size_t)1536 * RNN * 2;
    unsigned short* Whp  = (unsigned short*)wp;  wp += (size_t)16 * RNN * 2;
    __hip_bfloat16* h0   = (__hip_bfloat16*)wp;  wp += (size_t)NTOT * RNN * 2;
    __hip_bfloat16* gi   = (__hip_bfloat16*)wp;  wp += (size_t)NTOT * 1536 * 2;
    float* out = (float*)d_out;

    k_prep1<<<dim3(NTOT), dim3(320), 0, stream>>>(z, x, x_r_t0, W_sa, b_sa, zxb, a);
    k_prep_wcat<<<dim3(2048), dim3(320), 0, stream>>>(W_h0, W_ih, Wcat);
    k_prep_wp<<<dim3(192), dim3(512), 0, stream>>>(W_hh, Wp);
    k_prep_whp<<<dim3(4), dim3(256), 0, stream>>>(W_mu, W_ls, W_corr, Whp);
    k_gemm0_mfma<<<dim3(64, 16), dim3(256), 0, stream>>>(zxb, Wcat, b_h0, b_ih, h0, gi);
    k_rollout<<<dim3(256), dim3(512), 0, stream>>>(
        (const unsigned short*)h0, (const unsigned short*)gi, Wp, Whp,
        a, b_hh, W_ih, b_mu, b_ls, b_corr,
        eps_step, eps_fin, p0, out);
}